// Round 5
// baseline (1275.370 us; speedup 1.0000x reference)
//
#include <hip/hip_runtime.h>
#include <math.h>

#define HW 65536           // 256*256
typedef unsigned short u16;
typedef unsigned int   u32;
typedef __bf16 bf16_t;
typedef bf16_t bf16x8 __attribute__((ext_vector_type(8)));
typedef bf16_t bf16x2 __attribute__((ext_vector_type(2)));
typedef float  f32x4  __attribute__((ext_vector_type(4)));

#if defined(__has_builtin)
#if __has_builtin(__builtin_amdgcn_fdot2_f32_bf16)
#define HAS_FDOT2 1
#endif
#endif

__device__ __forceinline__ u16 f2bf(float x) {
    return __builtin_bit_cast(u16, (bf16_t)x);
}
__device__ __forceinline__ float bflo(u32 d) { return __uint_as_float(d << 16); }
__device__ __forceinline__ float bfhi(u32 d) { return __uint_as_float(d & 0xffff0000u); }

// ---------------------------------------------------------------------------
// Bias MLP: biasT[n][j][i] = ( relu(rel[i,j,:] @ w1^T + b1) @ w2^T + b2 )[n]
// ---------------------------------------------------------------------------
__global__ __launch_bounds__(256) void bias_mlp_kernel(
    const float* __restrict__ w1, const float* __restrict__ b1,
    const float* __restrict__ w2, const float* __restrict__ b2,
    float* __restrict__ biasT)
{
    int id = blockIdx.x * 256 + threadIdx.x;   // 4096 = 64*64
    int i = id >> 6, j = id & 63;
    float dy = (float)((i >> 3) - (j >> 3));
    float dx = (float)((i & 7) - (j & 7));
    float r0 = copysignf(log1pf(fabsf(dy)), dy);
    float r1 = copysignf(log1pf(fabsf(dx)), dx);
    float a0 = b2[0], a1 = b2[1], a2 = b2[2];
    for (int m = 0; m < 256; ++m) {
        float h = fmaf(r0, w1[2*m], fmaf(r1, w1[2*m+1], b1[m]));
        h = fmaxf(h, 0.f);
        a0 = fmaf(h, w2[m],       a0);
        a1 = fmaf(h, w2[256 + m], a1);
        a2 = fmaf(h, w2[512 + m], a2);
    }
    biasT[(0*64 + j)*64 + i] = a0;
    biasT[(1*64 + j)*64 + i] = a1;
    biasT[(2*64 + j)*64 + i] = a2;
}

// ---------------------------------------------------------------------------
// Fused QKV 1x1-conv GEMM via bf16 MFMA.  M=288 (Q|K|V), K=96, N-tile = 128
// positions arranged as an 8-row x 16-col image patch (= 2 whole 8x8 windows).
// 6 waves; wave w owns m-rows 48w..48w+47 (waves 0-1 Q, 2-3 K, 4-5 V).
// Q -> fp32 image layout.  K,V -> bf16 window-major [b][win][pos][ch],
// K pre-scaled by HD^-0.5 * exp(min(ls,log100)).
// ---------------------------------------------------------------------------
__global__ __launch_bounds__(384) void qkv_mfma_kernel(
    const float* __restrict__ X,  const float* __restrict__ Wq,
    const float* __restrict__ bq, const float* __restrict__ Wkv,
    const float* __restrict__ bkv, const float* __restrict__ lsptr,
    float* __restrict__ Qout, u16* __restrict__ Kw, u16* __restrict__ Vw)
{
    const int tid = threadIdx.x;
    int t = ((blockIdx.x & 7) * (gridDim.x >> 3)) + (blockIdx.x >> 3);
    const int b    = t >> 9;          // 512 tiles per image
    const int tile = t & 511;
    const int band = tile >> 4;       // window-row: rows band*8..band*8+7
    const int wcol = tile & 15;       // cols wcol*16..wcol*16+15

    __shared__ u16 Xs[128][104];      // [n][k] bf16, n = r*16+c, pad->208B rows

    const float* Xb = X + (size_t)band * 8 * 256 + wcol * 16 + (size_t)b * 96 * HW;

    #pragma unroll
    for (int j = 0; j < 8; ++j) {     // stage 96k x 128n fp32 -> bf16 transposed
        int i4 = tid + j * 384;       // 3072 float4
        int k  = i4 >> 5;
        int rr = (i4 >> 2) & 7;
        int c4 = (i4 & 3) * 4;
        float4 v = *reinterpret_cast<const float4*>(Xb + (size_t)k * HW + rr * 256 + c4);
        int n = rr * 16 + c4;
        Xs[n+0][k] = f2bf(v.x);
        Xs[n+1][k] = f2bf(v.y);
        Xs[n+2][k] = f2bf(v.z);
        Xs[n+3][k] = f2bf(v.w);
    }
    __syncthreads();

    const int wave = tid >> 6, l = tid & 63;
    const int m0 = wave * 48;
    const int lrow = l & 15, lq = l >> 4;

    f32x4 acc[3][8];
    #pragma unroll
    for (int mt = 0; mt < 3; ++mt)
        #pragma unroll
        for (int nt = 0; nt < 8; ++nt)
            acc[mt][nt] = (f32x4){0.f, 0.f, 0.f, 0.f};

    #pragma unroll
    for (int ks = 0; ks < 3; ++ks) {
        const int k0 = ks * 32 + lq * 8;
        bf16x8 afr[3];
        #pragma unroll
        for (int mt = 0; mt < 3; ++mt) {
            int m = m0 + mt * 16 + lrow;
            const float* Wrow = (m < 96) ? (Wq + m * 96) : (Wkv + (m - 96) * 96);
            float4 wa = *reinterpret_cast<const float4*>(Wrow + k0);
            float4 wb = *reinterpret_cast<const float4*>(Wrow + k0 + 4);
            bf16x8 af;
            af[0] = (bf16_t)wa.x; af[1] = (bf16_t)wa.y;
            af[2] = (bf16_t)wa.z; af[3] = (bf16_t)wa.w;
            af[4] = (bf16_t)wb.x; af[5] = (bf16_t)wb.y;
            af[6] = (bf16_t)wb.z; af[7] = (bf16_t)wb.w;
            afr[mt] = af;
        }
        #pragma unroll
        for (int nt = 0; nt < 8; ++nt) {
            bf16x8 bf = *reinterpret_cast<const bf16x8*>(&Xs[nt * 16 + lrow][k0]);
            #pragma unroll
            for (int mt = 0; mt < 3; ++mt)
                acc[mt][nt] = __builtin_amdgcn_mfma_f32_16x16x32_bf16(
                    afr[mt], bf, acc[mt][nt], 0, 0, 0);
        }
    }

    const float s = __expf(fminf(lsptr[0], 4.6051702f)) * 0.17677669529663687f;

    // epilogue.  C/D layout: col = lane&15, row = (lane>>4)*4 + reg  [m89/m91]
    #pragma unroll
    for (int mt = 0; mt < 3; ++mt) {
        #pragma unroll
        for (int nt = 0; nt < 8; ++nt) {
            #pragma unroll
            for (int r = 0; r < 4; ++r) {
                float v = acc[mt][nt][r];
                int o = m0 + mt * 16 + lq * 4 + r;
                if (o < 96) {          // Q -> fp32 image
                    Qout[(size_t)b * 96 * HW + (size_t)o * HW +
                         (band * 8 + nt) * 256 + wcol * 16 + lrow] = v + bq[o];
                } else {
                    int win = band * 32 + wcol * 2 + (lrow >> 3);
                    int wpos = nt * 8 + (lrow & 7);
                    size_t idx = ((size_t)(b * 1024 + win) * 64 + wpos) * 96;
                    if (o < 192) {     // K (scaled) -> bf16 window-major
                        int ch = o - 96;
                        Kw[idx + ch] = f2bf((v + bkv[ch]) * s);
                    } else {           // V -> bf16 window-major
                        int ch = o - 192;
                        Vw[idx + ch] = f2bf(v + bkv[96 + ch]);
                    }
                }
            }
        }
    }
}

// ---------------------------------------------------------------------------
// Depthwise 5x5, reflect-pad 2.  One block = one (b,c) and 8 image rows.
// ---------------------------------------------------------------------------
__global__ __launch_bounds__(256) void dwconv5x5_kernel(
    const float* __restrict__ Q, const float* __restrict__ dw,
    const float* __restrict__ db, float* __restrict__ out)
{
    int bid = (blockIdx.x & 7) * (gridDim.x >> 3) + (blockIdx.x >> 3);
    const int bc = bid >> 5;           // b_rel*96 + c
    const int h0 = (bid & 31) << 3;
    const int c  = bc % 96;
    const int tid = threadIdx.x;

    __shared__ float t[12][264];

    const float* Qb = Q + (size_t)bc * HW;
    #pragma unroll
    for (int jj = 0; jj < 3; ++jj) {
        int i4 = tid + jj*256;
        int r = i4 >> 6, c4 = i4 & 63;
        int imr = h0 - 2 + r;
        imr = imr < 0 ? -imr : (imr > 255 ? 510 - imr : imr);
        float4 v = *reinterpret_cast<const float4*>(Qb + imr*256 + c4*4);
        *reinterpret_cast<float4*>(&t[r][4 + c4*4]) = v;
    }
    if (tid < 48) {
        int r = tid >> 2, which = tid & 3;
        int imr = h0 - 2 + r;
        imr = imr < 0 ? -imr : (imr > 255 ? 510 - imr : imr);
        int L  = (which < 2) ? (2 + which) : (258 + which);
        int gc = (which == 0) ? 2 : (which == 1) ? 1 : (which == 2) ? 254 : 253;
        t[r][L] = Qb[imr*256 + gc];
    }
    __syncthreads();

    float w[25];
    #pragma unroll
    for (int q = 0; q < 25; ++q) w[q] = dw[c*25 + q];
    const float bv = db[c];

    float accv[8];
    #pragma unroll
    for (int r = 0; r < 8; ++r) accv[r] = bv;

    #pragma unroll
    for (int kx = 0; kx < 5; ++kx) {
        float col[12];
        #pragma unroll
        for (int rr = 0; rr < 12; ++rr) col[rr] = t[rr][tid + kx + 2];
        #pragma unroll
        for (int r = 0; r < 8; ++r)
            #pragma unroll
            for (int ky = 0; ky < 5; ++ky)
                accv[r] = fmaf(w[ky*5 + kx], col[r + ky], accv[r]);
    }

    float* ob = out + (size_t)bc * HW + h0*256 + tid;
    #pragma unroll
    for (int r = 0; r < 8; ++r)
        ob[r*256] = accv[r];
}

// ---------------------------------------------------------------------------
// Window attention.  Block = one window (192 thr = 3 waves = 3 heads),
// lane = query position.  K/V come in bf16 window-major (coalesced staging,
// 26.6 KB LDS -> 6 blocks/CU).  No-max softmax (logits structurally tiny).
// Output bf16 window-major (each lane writes one aligned 64B line).
// ---------------------------------------------------------------------------
__global__ __launch_bounds__(192) void winattn_kernel(
    const float* __restrict__ q, const u16* __restrict__ Kw,
    const u16* __restrict__ Vw, const float* __restrict__ biasT,
    u16* __restrict__ Ow)
{
    int t = (blockIdx.x & 7) * (gridDim.x >> 3) + (blockIdx.x >> 3);
    const int b = t >> 10, win = t & 1023;
    const int tid  = threadIdx.x;
    const int head = tid >> 6, lane = tid & 63;

    __shared__ u16 Kl[64][104];   // [pos][ch] bf16, 208B rows (16B-aligned)
    __shared__ u16 Vl[64][104];

    // q from conv-out (image layout fp32)
    const int wy = win >> 5, wx = win & 31;
    const int py = lane >> 3, px = lane & 7;
    const size_t qbase = (size_t)b * 96 * HW + (size_t)head * 32 * HW +
                         (size_t)(wy * 8 + py) * 256 + wx * 8 + px;
    float qr[32];
    #pragma unroll
    for (int d = 0; d < 32; ++d) qr[d] = q[qbase + (size_t)d * HW];

    // coalesced K/V staging: 12288 B each, contiguous
    const uint4* Kg = reinterpret_cast<const uint4*>(Kw + (size_t)(b * 1024 + win) * 6144);
    const uint4* Vg = reinterpret_cast<const uint4*>(Vw + (size_t)(b * 1024 + win) * 6144);
    #pragma unroll
    for (int j = 0; j < 4; ++j) {
        int i4 = tid + j * 192;            // 768 x 16B
        int n = i4 / 12, c8 = i4 % 12;
        *reinterpret_cast<uint4*>(&Kl[n][c8 * 8]) = Kg[i4];
        *reinterpret_cast<uint4*>(&Vl[n][c8 * 8]) = Vg[i4];
    }
    __syncthreads();

#ifdef HAS_FDOT2
    bf16x2 qp[16];
    #pragma unroll
    for (int i = 0; i < 16; ++i) {
        bf16x2 p; p[0] = (bf16_t)qr[2*i]; p[1] = (bf16_t)qr[2*i+1];
        qp[i] = p;
    }
#endif

    float acc[32];
    #pragma unroll
    for (int d = 0; d < 32; ++d) acc[d] = 0.f;
    float sum = 0.f;

    const float* bT = biasT + head * 4096 + lane;   // biasT[head][j][lane]
    #pragma unroll 4
    for (int j = 0; j < 64; ++j) {
        const uint4* kr = reinterpret_cast<const uint4*>(&Kl[j][head * 32]);
        uint4 ka = kr[0], kb = kr[1], kc = kr[2], kd = kr[3];
        float dot = bT[j * 64];
#ifdef HAS_FDOT2
        u32 kw[16] = {ka.x,ka.y,ka.z,ka.w, kb.x,kb.y,kb.z,kb.w,
                      kc.x,kc.y,kc.z,kc.w, kd.x,kd.y,kd.z,kd.w};
        #pragma unroll
        for (int i = 0; i < 16; ++i)
            dot = __builtin_amdgcn_fdot2_f32_bf16(
                qp[i], __builtin_bit_cast(bf16x2, kw[i]), dot, false);
#else
        u32 kw[16] = {ka.x,ka.y,ka.z,ka.w, kb.x,kb.y,kb.z,kb.w,
                      kc.x,kc.y,kc.z,kc.w, kd.x,kd.y,kd.z,kd.w};
        #pragma unroll
        for (int i = 0; i < 16; ++i) {
            dot = fmaf(qr[2*i],   bflo(kw[i]), dot);
            dot = fmaf(qr[2*i+1], bfhi(kw[i]), dot);
        }
#endif
        float p = __expf(dot);
        sum += p;
        const uint4* vr = reinterpret_cast<const uint4*>(&Vl[j][head * 32]);
        uint4 va = vr[0], vb = vr[1], vc = vr[2], vd = vr[3];
        u32 vw[16] = {va.x,va.y,va.z,va.w, vb.x,vb.y,vb.z,vb.w,
                      vc.x,vc.y,vc.z,vc.w, vd.x,vd.y,vd.z,vd.w};
        #pragma unroll
        for (int i = 0; i < 16; ++i) {
            acc[2*i]   = fmaf(p, bflo(vw[i]), acc[2*i]);
            acc[2*i+1] = fmaf(p, bfhi(vw[i]), acc[2*i+1]);
        }
    }

    const float inv = 1.0f / sum;
    // pack 32 bf16 -> one aligned 64B line per lane
    u32 ow[16];
    #pragma unroll
    for (int i = 0; i < 16; ++i) {
        u32 lo = f2bf(acc[2*i]   * inv);
        u32 hi = f2bf(acc[2*i+1] * inv);
        ow[i] = lo | (hi << 16);
    }
    uint4* ob = reinterpret_cast<uint4*>(
        Ow + ((size_t)(b * 1024 + win) * 64 + lane) * 96 + head * 32);
    ob[0] = (uint4){ow[0],  ow[1],  ow[2],  ow[3]};
    ob[1] = (uint4){ow[4],  ow[5],  ow[6],  ow[7]};
    ob[2] = (uint4){ow[8],  ow[9],  ow[10], ow[11]};
    ob[3] = (uint4){ow[12], ow[13], ow[14], ow[15]};
}

// ---------------------------------------------------------------------------
// Projection GEMM via bf16 MFMA.  A = Wproj (96x96), B = attn-out in
// window-major bf16 ([pos][ch] = B^T, so LDS staging is a straight copy).
// N-tile = 2 windows = 128 pos.  3 waves; wave w owns m-rows 32w..32w+31.
// Output fp32 image + bproj.
// ---------------------------------------------------------------------------
__global__ __launch_bounds__(192) void proj_mfma_kernel(
    const u16* __restrict__ Aw, const float* __restrict__ Wproj,
    const float* __restrict__ bproj, float* __restrict__ out)
{
    const int tid = threadIdx.x;
    int t = ((blockIdx.x & 7) * (gridDim.x >> 3)) + (blockIdx.x >> 3);
    const int b    = t >> 9;
    const int tile = t & 511;
    const int band = tile >> 4;       // window row
    const int wp   = tile & 15;       // window pair (cols wp*16..wp*16+15)

    __shared__ u16 Xs[128][104];      // [n][k], n = win_local*64 + wpos

    const uint4* Ag = reinterpret_cast<const uint4*>(
        Aw + (size_t)(b * 1024 + band * 32 + wp * 2) * 6144);
    #pragma unroll
    for (int j = 0; j < 8; ++j) {
        int i4 = tid + j * 192;            // 1536 x 16B
        int n = i4 / 12, c8 = i4 % 12;
        *reinterpret_cast<uint4*>(&Xs[n][c8 * 8]) = Ag[i4];
    }
    __syncthreads();

    const int wave = tid >> 6, l = tid & 63;
    const int m0 = wave * 32;
    const int lrow = l & 15, lq = l >> 4;

    f32x4 acc[2][8];
    #pragma unroll
    for (int mt = 0; mt < 2; ++mt)
        #pragma unroll
        for (int nt = 0; nt < 8; ++nt)
            acc[mt][nt] = (f32x4){0.f, 0.f, 0.f, 0.f};

    #pragma unroll
    for (int ks = 0; ks < 3; ++ks) {
        const int k0 = ks * 32 + lq * 8;
        bf16x8 afr[2];
        #pragma unroll
        for (int mt = 0; mt < 2; ++mt) {
            const float* Wrow = Wproj + (m0 + mt * 16 + lrow) * 96;
            float4 wa = *reinterpret_cast<const float4*>(Wrow + k0);
            float4 wb = *reinterpret_cast<const float4*>(Wrow + k0 + 4);
            bf16x8 af;
            af[0] = (bf16_t)wa.x; af[1] = (bf16_t)wa.y;
            af[2] = (bf16_t)wa.z; af[3] = (bf16_t)wa.w;
            af[4] = (bf16_t)wb.x; af[5] = (bf16_t)wb.y;
            af[6] = (bf16_t)wb.z; af[7] = (bf16_t)wb.w;
            afr[mt] = af;
        }
        #pragma unroll
        for (int nt = 0; nt < 8; ++nt) {
            bf16x8 bf = *reinterpret_cast<const bf16x8*>(&Xs[nt * 16 + lrow][k0]);
            #pragma unroll
            for (int mt = 0; mt < 2; ++mt)
                acc[mt][nt] = __builtin_amdgcn_mfma_f32_16x16x32_bf16(
                    afr[mt], bf, acc[mt][nt], 0, 0, 0);
        }
    }

    #pragma unroll
    for (int mt = 0; mt < 2; ++mt) {
        #pragma unroll
        for (int nt = 0; nt < 8; ++nt) {
            #pragma unroll
            for (int r = 0; r < 4; ++r) {
                int o = m0 + mt * 16 + lq * 4 + r;
                int n = nt * 16 + lrow;
                int wl = n >> 6, wpos = n & 63;
                int h = band * 8 + (wpos >> 3);
                int wimg = wp * 16 + wl * 8 + (wpos & 7);
                out[(size_t)b * 96 * HW + (size_t)o * HW + h * 256 + wimg] =
                    acc[mt][nt][r] + bproj[o];
            }
        }
    }
}

// ---------------------------------------------------------------------------
extern "C" void kernel_launch(void* const* d_in, const int* in_sizes, int n_in,
                              void* d_out, int out_size, void* d_ws, size_t ws_size,
                              hipStream_t stream)
{
    const float* X     = (const float*)d_in[0];
    const float* Wq    = (const float*)d_in[1];
    const float* bq    = (const float*)d_in[2];
    const float* Wkv   = (const float*)d_in[3];
    const float* bkv   = (const float*)d_in[4];
    const float* dww   = (const float*)d_in[5];
    const float* dwb   = (const float*)d_in[6];
    const float* Wproj = (const float*)d_in[7];
    const float* bproj = (const float*)d_in[8];
    const float* ls    = (const float*)d_in[9];
    const float* mw1   = (const float*)d_in[10];
    const float* mb1   = (const float*)d_in[11];
    const float* mw2   = (const float*)d_in[12];
    const float* mb2   = (const float*)d_in[13];
    float* out = (float*)d_out;

    // Scratch layout: biasT (48KB) + f0 (Q fp32 image, later reused as bf16
    // attn-out) + Kw + Vw (bf16 window-major).  convQ lives in d_out.
    const size_t perBatch = (size_t)96 * HW;
    int nb = 8;
    while (nb > 1 &&
           49152 + (size_t)nb * perBatch * 8 > ws_size)
        nb >>= 1;

    float* biasT = (float*)d_ws;                       // [3][64][64]
    float* f0    = biasT + 12288;                      // Q fp32 / attn-out bf16
    u16*   Kw    = (u16*)(f0 + (size_t)nb * perBatch); // K bf16 window-major
    u16*   Vw    = Kw + (size_t)nb * perBatch;         // V bf16 window-major

    bias_mlp_kernel<<<16, 256, 0, stream>>>(mw1, mb1, mw2, mb2, biasT);

    for (int b0 = 0; b0 < 8; b0 += nb) {
        const float* Xc = X   + (size_t)b0 * perBatch;
        float*       oc = out + (size_t)b0 * perBatch;  // convQ scratch / final out
        qkv_mfma_kernel<<<512 * nb, 384, 0, stream>>>(
            Xc, Wq, bq, Wkv, bkv, ls, f0, Kw, Vw);
        dwconv5x5_kernel<<<3072 * nb, 256, 0, stream>>>(f0, dww, dwb, oc);
        winattn_kernel<<<1024 * nb, 192, 0, stream>>>(
            oc, Kw, Vw, biasT, (u16*)f0);
        proj_mfma_kernel<<<512 * nb, 192, 0, stream>>>(
            (u16*)f0, Wproj, bproj, oc);
    }
}